// Round 1
// baseline (225.090 us; speedup 1.0000x reference)
//
#include <hip/hip_runtime.h>
#include <hip/hip_bf16.h>

// Problem constants (fixed by reference)
#define DIMC 1024
#define HEADS 16
#define HEAD_DIM 64
#define KWIN 13
#define NSH 6
#define LSEQ 4096
#define BATCH 2
#define NROWS (BATCH*LSEQ)        // 8192 token rows
#define QKV_N (3*DIMC)            // 3072
#define SCALE_Q 0.125f            // 64^-0.5

typedef __attribute__((ext_vector_type(4))) float f32x4;
typedef __attribute__((ext_vector_type(8))) short bf16x8;

__device__ __forceinline__ void gload_lds16(const void* g, void* l) {
  __builtin_amdgcn_global_load_lds(
      (const __attribute__((address_space(1))) void*)g,
      (__attribute__((address_space(3))) void*)l, 16, 0, 0);
}

// ---------------- cast fp32 -> bf16 (vectorized) ----------------
__global__ __launch_bounds__(256) void cast_kernel(const float* __restrict__ in,
                                                   __hip_bfloat16* __restrict__ out,
                                                   int n4) {
  int i = blockIdx.x * 256 + threadIdx.x;
  if (i >= n4) return;
  float4 v = ((const float4*)in)[i];
  union { short4 s; __hip_bfloat16 h[4]; } u;
  u.h[0] = __float2bfloat16(v.x);
  u.h[1] = __float2bfloat16(v.y);
  u.h[2] = __float2bfloat16(v.z);
  u.h[3] = __float2bfloat16(v.w);
  ((short4*)out)[i] = u.s;
}

// ---------------- bf16 GEMM: C[M][N] = A[M][K] * B[N][K]^T + bias ----------------
// 128x128 tile, BK=32, 256 threads (4 waves, 2x2 wave grid of 64x64 subtiles),
// global_load_lds width=16 staging, mfma_f32_16x16x32_bf16.
template<int OUT_BF16>
__global__ __launch_bounds__(256) void gemm_bt(const __hip_bfloat16* __restrict__ A,
                                               const __hip_bfloat16* __restrict__ B,
                                               const float* __restrict__ bias,
                                               void* __restrict__ Cout,
                                               int M, int N, int K) {
  __shared__ __align__(16) __hip_bfloat16 As[128 * 32];
  __shared__ __align__(16) __hip_bfloat16 Bs[128 * 32];

  const int tid  = threadIdx.x;
  const int lane = tid & 63;
  const int wave = tid >> 6;
  const int m0 = blockIdx.y * 128;
  const int n0 = blockIdx.x * 128;
  const int wr = wave >> 1;   // 0..1
  const int wc = wave & 1;    // 0..1

  f32x4 acc[4][4] = {};

  // staging map: wave covers LDS elements [wave*1024, wave*1024+1024) in 2 calls
  // call c: rows wave*32 + c*16 + (lane>>2), col elems (lane&3)*8
  const int rA0  = wave * 32 + (lane >> 2);
  const int kcol = (lane & 3) * 8;
  const __hip_bfloat16* gA = A + (size_t)(m0 + rA0) * K + kcol;
  const __hip_bfloat16* gB = B + (size_t)(n0 + rA0) * K + kcol;
  __hip_bfloat16* lA0 = As + wave * 1024;
  __hip_bfloat16* lA1 = As + wave * 1024 + 512;
  __hip_bfloat16* lB0 = Bs + wave * 1024;
  __hip_bfloat16* lB1 = Bs + wave * 1024 + 512;

  const int fr = lane & 15;
  const int fk = (lane >> 4) * 8;

  for (int k0 = 0; k0 < K; k0 += 32) {
    gload_lds16(gA,                 lA0);
    gload_lds16(gA + (size_t)16 * K, lA1);
    gload_lds16(gB,                 lB0);
    gload_lds16(gB + (size_t)16 * K, lB1);
    gA += 32;
    gB += 32;
    __syncthreads();   // compiler drains vmcnt before s_barrier

    bf16x8 af[4], bfr[4];
#pragma unroll
    for (int i = 0; i < 4; i++)
      af[i] = *(const bf16x8*)&As[(wr * 64 + i * 16 + fr) * 32 + fk];
#pragma unroll
    for (int i = 0; i < 4; i++)
      bfr[i] = *(const bf16x8*)&Bs[(wc * 64 + i * 16 + fr) * 32 + fk];

#pragma unroll
    for (int mi = 0; mi < 4; mi++)
#pragma unroll
      for (int ni = 0; ni < 4; ni++)
        acc[mi][ni] = __builtin_amdgcn_mfma_f32_16x16x32_bf16(af[mi], bfr[ni], acc[mi][ni], 0, 0, 0);

    __syncthreads();
  }

  // epilogue: C/D layout col = lane&15, row = (lane>>4)*4 + reg
#pragma unroll
  for (int ni = 0; ni < 4; ni++) {
    const int col = n0 + wc * 64 + ni * 16 + (lane & 15);
    const float bv = bias[col];
#pragma unroll
    for (int mi = 0; mi < 4; mi++) {
      const int row = m0 + wr * 64 + mi * 16 + ((lane >> 4) << 2);
#pragma unroll
      for (int i = 0; i < 4; i++) {
        const float v = acc[mi][ni][i] + bv;
        if (OUT_BF16)
          ((__hip_bfloat16*)Cout)[(size_t)(row + i) * N + col] = __float2bfloat16(v);
        else
          ((float*)Cout)[(size_t)(row + i) * N + col] = v;
      }
    }
  }
}

// ---------------- neighborhood attention (K=13 window) ----------------
// one wave per (b,l,h); lane = head-dim element.
__global__ __launch_bounds__(256) void natten(const __hip_bfloat16* __restrict__ qkv,
                                              const float* __restrict__ rpb,
                                              __hip_bfloat16* __restrict__ att) {
  const int gw   = (blockIdx.x * 256 + threadIdx.x) >> 6;
  const int lane = threadIdx.x & 63;
  const int h  = gw & (HEADS - 1);
  const int bl = gw >> 4;              // b*L + l, 0..8191
  const int l  = bl & (LSEQ - 1);

  int ni = l - NSH;
  ni = ni < 0 ? 0 : (ni > LSEQ - KWIN ? LSEQ - KWIN : ni);
  const int pi = NSH + (l < NSH ? NSH - l : 0) + (l + NSH >= LSEQ ? LSEQ - l - 1 - NSH : 0);

  const float qd = SCALE_Q * __bfloat162float(qkv[(size_t)bl * QKV_N + h * HEAD_DIM + lane]);
  const __hip_bfloat16* kbase = qkv + (size_t)(bl - l + ni) * QKV_N + DIMC + h * HEAD_DIM + lane;
  const float* rp = rpb + h * (2 * KWIN - 1) + pi;

  float sc[KWIN];
#pragma unroll
  for (int j = 0; j < KWIN; j++) {
    float p = qd * __bfloat162float(kbase[(size_t)j * QKV_N]);
    p += __shfl_xor(p, 32);
    p += __shfl_xor(p, 16);
    p += __shfl_xor(p, 8);
    p += __shfl_xor(p, 4);
    p += __shfl_xor(p, 2);
    p += __shfl_xor(p, 1);
    sc[j] = p + rp[j];
  }

  float m = sc[0];
#pragma unroll
  for (int j = 1; j < KWIN; j++) m = fmaxf(m, sc[j]);
  float s = 0.f;
#pragma unroll
  for (int j = 0; j < KWIN; j++) { sc[j] = __expf(sc[j] - m); s += sc[j]; }
  const float inv = 1.f / s;

  const __hip_bfloat16* vbase = kbase + DIMC;
  float o = 0.f;
#pragma unroll
  for (int j = 0; j < KWIN; j++) o += sc[j] * __bfloat162float(vbase[(size_t)j * QKV_N]);

  att[(size_t)bl * DIMC + h * HEAD_DIM + lane] = __float2bfloat16(o * inv);
}

// ---------------- launch ----------------
extern "C" void kernel_launch(void* const* d_in, const int* in_sizes, int n_in,
                              void* d_out, int out_size, void* d_ws, size_t ws_size,
                              hipStream_t stream) {
  const float* x      = (const float*)d_in[0];
  const float* qkv_w  = (const float*)d_in[1];
  const float* qkv_b  = (const float*)d_in[2];
  const float* rpb    = (const float*)d_in[3];
  const float* proj_w = (const float*)d_in[4];
  const float* proj_b = (const float*)d_in[5];
  float* out = (float*)d_out;

  // workspace layout (bytes):
  //   xb    @ 0         : 8192*1024  bf16 = 16,777,216
  //   wqkv  @ 16777216  : 3072*1024  bf16 =  6,291,456
  //   wproj @ 23068672  : 1024*1024  bf16 =  2,097,152
  //   qkv   @ 25165824  : 8192*3072  bf16 = 50,331,648
  //   att   @ 75497472  : 8192*1024  bf16 = 16,777,216
  // total 92,274,688 B
  char* ws = (char*)d_ws;
  __hip_bfloat16* xb    = (__hip_bfloat16*)(ws);
  __hip_bfloat16* wqkv  = (__hip_bfloat16*)(ws + 16777216);
  __hip_bfloat16* wproj = (__hip_bfloat16*)(ws + 23068672);
  __hip_bfloat16* qkv   = (__hip_bfloat16*)(ws + 25165824);
  __hip_bfloat16* att   = (__hip_bfloat16*)(ws + 75497472);

  cast_kernel<<<(NROWS * DIMC / 4 + 255) / 256, 256, 0, stream>>>(x, xb, NROWS * DIMC / 4);
  cast_kernel<<<(QKV_N * DIMC / 4 + 255) / 256, 256, 0, stream>>>(qkv_w, wqkv, QKV_N * DIMC / 4);
  cast_kernel<<<(DIMC * DIMC / 4 + 255) / 256, 256, 0, stream>>>(proj_w, wproj, DIMC * DIMC / 4);

  gemm_bt<1><<<dim3(QKV_N / 128, NROWS / 128), 256, 0, stream>>>(
      xb, wqkv, qkv_b, (void*)qkv, NROWS, QKV_N, DIMC);

  natten<<<(NROWS * HEADS) / 4, 256, 0, stream>>>(qkv, rpb, att);

  gemm_bt<0><<<dim3(DIMC / 128, NROWS / 128), 256, 0, stream>>>(
      att, wproj, proj_b, (void*)out, NROWS, DIMC, DIMC);
}

// Round 2
// 149.471 us; speedup vs baseline: 1.5059x; 1.5059x over previous
//
#include <hip/hip_runtime.h>
#include <hip/hip_bf16.h>

// Problem constants (fixed by reference)
#define DIMC 1024
#define HEADS 16
#define HEAD_DIM 64
#define KWIN 13
#define NSH 6
#define LSEQ 4096
#define BATCH 2
#define NROWS (BATCH*LSEQ)        // 8192 token rows
#define QKV_N (3*DIMC)            // 3072
#define SCALE_Q 0.125f            // 64^-0.5

#define TBLK 256                  // tokens per natten block
#define WROWS 268                 // staged K/V window rows (256 + 12)

typedef __attribute__((ext_vector_type(4))) float f32x4;
typedef __attribute__((ext_vector_type(8))) short bf16x8;

__device__ __forceinline__ void gload_lds16(const void* g, void* l) {
  __builtin_amdgcn_global_load_lds(
      (const __attribute__((address_space(1))) void*)g,
      (__attribute__((address_space(3))) void*)l, 16, 0, 0);
}

// unpack 8 bf16 (in uint4) -> 8 f32
__device__ __forceinline__ void cvt8(uint4 r, float* f) {
  unsigned u[4] = {r.x, r.y, r.z, r.w};
#pragma unroll
  for (int w = 0; w < 4; w++) {
    f[2*w]   = __uint_as_float(u[w] << 16);
    f[2*w+1] = __uint_as_float(u[w] & 0xffff0000u);
  }
}

// ---------------- cast fp32 -> bf16 (vectorized) ----------------
__global__ __launch_bounds__(256) void cast_kernel(const float* __restrict__ in,
                                                   __hip_bfloat16* __restrict__ out,
                                                   int n4) {
  int i = blockIdx.x * 256 + threadIdx.x;
  if (i >= n4) return;
  float4 v = ((const float4*)in)[i];
  union { short4 s; __hip_bfloat16 h[4]; } u;
  u.h[0] = __float2bfloat16(v.x);
  u.h[1] = __float2bfloat16(v.y);
  u.h[2] = __float2bfloat16(v.z);
  u.h[3] = __float2bfloat16(v.w);
  ((short4*)out)[i] = u.s;
}

// ---------------- bf16 GEMM: C[M][N] = A[M][K] * B[N][K]^T + bias ----------------
template<int OUT_BF16>
__global__ __launch_bounds__(256) void gemm_bt(const __hip_bfloat16* __restrict__ A,
                                               const __hip_bfloat16* __restrict__ B,
                                               const float* __restrict__ bias,
                                               void* __restrict__ Cout,
                                               int M, int N, int K) {
  __shared__ __align__(16) __hip_bfloat16 As[128 * 32];
  __shared__ __align__(16) __hip_bfloat16 Bs[128 * 32];

  const int tid  = threadIdx.x;
  const int lane = tid & 63;
  const int wave = tid >> 6;
  const int m0 = blockIdx.y * 128;
  const int n0 = blockIdx.x * 128;
  const int wr = wave >> 1;
  const int wc = wave & 1;

  f32x4 acc[4][4] = {};

  const int rA0  = wave * 32 + (lane >> 2);
  const int kcol = (lane & 3) * 8;
  const __hip_bfloat16* gA = A + (size_t)(m0 + rA0) * K + kcol;
  const __hip_bfloat16* gB = B + (size_t)(n0 + rA0) * K + kcol;
  __hip_bfloat16* lA0 = As + wave * 1024;
  __hip_bfloat16* lA1 = As + wave * 1024 + 512;
  __hip_bfloat16* lB0 = Bs + wave * 1024;
  __hip_bfloat16* lB1 = Bs + wave * 1024 + 512;

  const int fr = lane & 15;
  const int fk = (lane >> 4) * 8;

  for (int k0 = 0; k0 < K; k0 += 32) {
    gload_lds16(gA,                  lA0);
    gload_lds16(gA + (size_t)16 * K, lA1);
    gload_lds16(gB,                  lB0);
    gload_lds16(gB + (size_t)16 * K, lB1);
    gA += 32;
    gB += 32;
    __syncthreads();

    bf16x8 af[4], bfr[4];
#pragma unroll
    for (int i = 0; i < 4; i++)
      af[i] = *(const bf16x8*)&As[(wr * 64 + i * 16 + fr) * 32 + fk];
#pragma unroll
    for (int i = 0; i < 4; i++)
      bfr[i] = *(const bf16x8*)&Bs[(wc * 64 + i * 16 + fr) * 32 + fk];

#pragma unroll
    for (int mi = 0; mi < 4; mi++)
#pragma unroll
      for (int ni = 0; ni < 4; ni++)
        acc[mi][ni] = __builtin_amdgcn_mfma_f32_16x16x32_bf16(af[mi], bfr[ni], acc[mi][ni], 0, 0, 0);

    __syncthreads();
  }

#pragma unroll
  for (int ni = 0; ni < 4; ni++) {
    const int col = n0 + wc * 64 + ni * 16 + (lane & 15);
    const float bv = bias[col];
#pragma unroll
    for (int mi = 0; mi < 4; mi++) {
      const int row = m0 + wr * 64 + mi * 16 + ((lane >> 4) << 2);
#pragma unroll
      for (int i = 0; i < 4; i++) {
        const float v = acc[mi][ni][i] + bv;
        if (OUT_BF16)
          ((__hip_bfloat16*)Cout)[(size_t)(row + i) * N + col] = __float2bfloat16(v);
        else
          ((float*)Cout)[(size_t)(row + i) * N + col] = v;
      }
    }
  }
}

// ---------------- neighborhood attention: lane-per-token ----------------
// block = 256 threads = 256 tokens of one (b,h). K/V window staged in LDS
// with XOR swizzle; softmax entirely lane-local (no shuffles).
__global__ __launch_bounds__(256, 2) void natten(const __hip_bfloat16* __restrict__ qkv,
                                                 const float* __restrict__ rpb,
                                                 __hip_bfloat16* __restrict__ att) {
  __shared__ __align__(16) unsigned char smem[2 * WROWS * 128];  // K then V, swizzled

  const int tid = threadIdx.x;
  const int tb  = blockIdx.x;   // token block (0..15)
  const int h   = blockIdx.y;
  const int b   = blockIdx.z;
  const int t0  = tb * TBLK;

  int r0 = t0 - NSH;
  if (r0 < 0) r0 = 0;
  if (r0 > LSEQ - WROWS) r0 = LSEQ - WROWS;

  // ---- stage K/V rows [r0, r0+WROWS) for this (b,h), swizzled ----
  const __hip_bfloat16* kg = qkv + ((size_t)b * LSEQ + r0) * QKV_N + DIMC + h * HEAD_DIM;
  const __hip_bfloat16* vg = kg + DIMC;
#pragma unroll 1
  for (int i = tid; i < WROWS * 8; i += 256) {
    const int row = i >> 3, c = i & 7;
    const uint4 kk = *(const uint4*)(kg + (size_t)row * QKV_N + c * 8);
    const uint4 vv = *(const uint4*)(vg + (size_t)row * QKV_N + c * 8);
    const int off = row * 128 + ((c * 16) ^ ((row & 7) << 4));
    *(uint4*)(smem + off) = kk;
    *(uint4*)(smem + WROWS * 128 + off) = vv;
  }
  __syncthreads();

  // ---- per-lane token ----
  const int t = t0 + tid;
  int ni = t - NSH;
  ni = ni < 0 ? 0 : (ni > LSEQ - KWIN ? LSEQ - KWIN : ni);
  const int rbase = ni - r0;   // 0..255
  const int pi = NSH + (t < NSH ? NSH - t : 0) + (t + NSH >= LSEQ ? LSEQ - t - 1 - NSH : 0);
  const float* rp = rpb + h * (2 * KWIN - 1) + pi;

  // Q -> 64 f32 registers (rows L2-cached; all bytes of each line used)
  const __hip_bfloat16* qg = qkv + ((size_t)b * LSEQ + t) * QKV_N + h * HEAD_DIM;
  float qf[64];
#pragma unroll
  for (int c = 0; c < 8; c++) {
    uint4 qq = *(const uint4*)(qg + c * 8);
    cvt8(qq, qf + c * 8);
  }

  // ---- scores ----
  float p[KWIN];
#pragma unroll
  for (int j = 0; j < KWIN; j++) {
    const int row = rbase + j;
    const int sw = (row & 7) << 4;
    float s = 0.f;
#pragma unroll
    for (int c = 0; c < 8; c++) {
      uint4 kk = *(const uint4*)(smem + row * 128 + ((c * 16) ^ sw));
      float kf[8];
      cvt8(kk, kf);
#pragma unroll
      for (int e = 0; e < 8; e++) s += qf[c * 8 + e] * kf[e];
    }
    p[j] = s * SCALE_Q + rp[j];
  }

  // ---- softmax (lane-local) ----
  float m = p[0];
#pragma unroll
  for (int j = 1; j < KWIN; j++) m = fmaxf(m, p[j]);
  float sum = 0.f;
#pragma unroll
  for (int j = 0; j < KWIN; j++) { p[j] = __expf(p[j] - m); sum += p[j]; }
  const float inv = 1.f / sum;
#pragma unroll
  for (int j = 0; j < KWIN; j++) p[j] *= inv;

  // ---- PV, 8 dims at a time ----
  __hip_bfloat16* og = att + ((size_t)b * LSEQ + t) * DIMC + h * HEAD_DIM;
#pragma unroll
  for (int c = 0; c < 8; c++) {
    float acc[8] = {0.f, 0.f, 0.f, 0.f, 0.f, 0.f, 0.f, 0.f};
#pragma unroll
    for (int j = 0; j < KWIN; j++) {
      const int row = rbase + j;
      uint4 vv = *(const uint4*)(smem + WROWS * 128 + row * 128 + ((c * 16) ^ ((row & 7) << 4)));
      float vf[8];
      cvt8(vv, vf);
#pragma unroll
      for (int e = 0; e < 8; e++) acc[e] += p[j] * vf[e];
    }
    union { ushort us[8]; uint4 v; } o;
#pragma unroll
    for (int e = 0; e < 8; e++) {
      __hip_bfloat16 hb = __float2bfloat16(acc[e]);
      o.us[e] = *(ushort*)&hb;
    }
    *(uint4*)(og + c * 8) = o.v;
  }
}

// ---------------- launch ----------------
extern "C" void kernel_launch(void* const* d_in, const int* in_sizes, int n_in,
                              void* d_out, int out_size, void* d_ws, size_t ws_size,
                              hipStream_t stream) {
  const float* x      = (const float*)d_in[0];
  const float* qkv_w  = (const float*)d_in[1];
  const float* qkv_b  = (const float*)d_in[2];
  const float* rpb    = (const float*)d_in[3];
  const float* proj_w = (const float*)d_in[4];
  const float* proj_b = (const float*)d_in[5];
  float* out = (float*)d_out;

  char* ws = (char*)d_ws;
  __hip_bfloat16* xb    = (__hip_bfloat16*)(ws);
  __hip_bfloat16* wqkv  = (__hip_bfloat16*)(ws + 16777216);
  __hip_bfloat16* wproj = (__hip_bfloat16*)(ws + 23068672);
  __hip_bfloat16* qkv   = (__hip_bfloat16*)(ws + 25165824);
  __hip_bfloat16* att   = (__hip_bfloat16*)(ws + 75497472);

  cast_kernel<<<(NROWS * DIMC / 4 + 255) / 256, 256, 0, stream>>>(x, xb, NROWS * DIMC / 4);
  cast_kernel<<<(QKV_N * DIMC / 4 + 255) / 256, 256, 0, stream>>>(qkv_w, wqkv, QKV_N * DIMC / 4);
  cast_kernel<<<(DIMC * DIMC / 4 + 255) / 256, 256, 0, stream>>>(proj_w, wproj, DIMC * DIMC / 4);

  gemm_bt<1><<<dim3(QKV_N / 128, NROWS / 128), 256, 0, stream>>>(
      xb, wqkv, qkv_b, (void*)qkv, NROWS, QKV_N, DIMC);

  natten<<<dim3(LSEQ / TBLK, HEADS, BATCH), 256, 0, stream>>>(qkv, rpb, att);

  gemm_bt<0><<<dim3(DIMC / 128, NROWS / 128), 256, 0, stream>>>(
      att, wproj, proj_b, (void*)out, NROWS, DIMC, DIMC);
}